// Round 11
// baseline (827.410 us; speedup 1.0000x reference)
//
#include <hip/hip_runtime.h>
#include <hip/hip_bf16.h>

typedef unsigned short u16;
typedef unsigned int   u32;
typedef __attribute__((ext_vector_type(8))) short short8;
typedef __attribute__((ext_vector_type(4))) float floatx4;
typedef __attribute__((ext_vector_type(2))) float floatx2;

__device__ __forceinline__ float bits2f(u32 v){ float f; __builtin_memcpy(&f, &v, 4); return f; }
__device__ __forceinline__ u16 f2bf(float f){
    __hip_bfloat16 h = __float2bfloat16(f);
    u16 u; __builtin_memcpy(&u, &h, 2); return u;
}

// ---------------- f32 -> bf16 conversion (x into hbuf) ----------------

__global__ __launch_bounds__(256) void cvt_kernel(const float* __restrict__ in,
                                                  u16* __restrict__ out, int total4){
    int i = blockIdx.x * 256 + threadIdx.x;
    if (i >= total4) return;
    float4 v = ((const float4*)in)[i];
    uint2 o;
    o.x = (u32)f2bf(v.x) | ((u32)f2bf(v.y) << 16);
    o.y = (u32)f2bf(v.z) | ((u32)f2bf(v.w) << 16);
    ((uint2*)out)[i] = o;
}

// ---------------- CSR build: bucket hist -> bucket scan -> multisplit bin -> bucket sort ----------------

__global__ __launch_bounds__(256) void bhist_kernel(const int* __restrict__ dst,
                                                    int* __restrict__ gbcnt, int E){
    __shared__ int bc[256];
    const int t = threadIdx.x;
    bc[t] = 0;
    __syncthreads();
    const int tile0 = blockIdx.x * 8192;
    const int cnt = min(8192, E - tile0);
    for (int j = t; j < cnt; j += 256) atomicAdd(&bc[dst[tile0 + j] >> 9], 1);
    __syncthreads();
    if (bc[t] > 0) atomicAdd(&gbcnt[t], bc[t]);
}

__global__ __launch_bounds__(256) void bscan_kernel(const int* __restrict__ gbcnt,
                                                    int* __restrict__ bbase,
                                                    int* __restrict__ bcur, int nbuk){
    __shared__ int ws[4];
    const int t = threadIdx.x, lane = t & 63, wv = t >> 6;
    int v = (t < nbuk) ? gbcnt[t] : 0;
    int s = v;
    for (int off = 1; off < 64; off <<= 1){
        int n = __shfl_up(s, off);
        if (lane >= off) s += n;
    }
    if (lane == 63) ws[wv] = s;
    __syncthreads();
    int woff = 0;
    for (int w = 0; w < wv; ++w) woff += ws[w];
    int excl = s + woff - v;
    if (t < nbuk){ bbase[t] = excl; bcur[t] = excl; }
}

#define BIN_TILE 8192
__global__ __launch_bounds__(256) void bin_kernel(const int* __restrict__ src,
                                                  const int* __restrict__ dst,
                                                  int* __restrict__ bcur,
                                                  u32* __restrict__ pairs, int E, int nbuk){
    __shared__ u32 hcnt[256], hexcl[256], hoff[256];
    __shared__ int gbase[256];
    __shared__ u32 stage[BIN_TILE];
    __shared__ unsigned char bkt[BIN_TILE];
    const int t = threadIdx.x;
    const int tile0 = blockIdx.x * BIN_TILE;
    const int cntE = min(BIN_TILE, E - tile0);

    hcnt[t] = 0;
    __syncthreads();
    for (int j = t; j < cntE; j += 256){
        int d = dst[tile0 + j];
        atomicAdd(&hcnt[d >> 9], 1u);
    }
    __syncthreads();
    if (t < 64){
        u32 a0 = hcnt[4*t], a1 = hcnt[4*t+1], a2 = hcnt[4*t+2], a3 = hcnt[4*t+3];
        u32 lsum = a0 + a1 + a2 + a3;
        u32 s = lsum;
        for (int off = 1; off < 64; off <<= 1){
            u32 n = __shfl_up(s, off);
            if (t >= off) s += n;
        }
        u32 base = s - lsum;
        hexcl[4*t]   = base;
        hexcl[4*t+1] = base + a0;
        hexcl[4*t+2] = base + a0 + a1;
        hexcl[4*t+3] = base + a0 + a1 + a2;
        hoff[4*t]   = base;
        hoff[4*t+1] = base + a0;
        hoff[4*t+2] = base + a0 + a1;
        hoff[4*t+3] = base + a0 + a1 + a2;
    }
    __syncthreads();
    if (t < nbuk && hcnt[t] > 0) gbase[t] = atomicAdd(&bcur[t], (int)hcnt[t]);
    for (int j = t; j < cntE; j += 256){
        int d = dst[tile0 + j];
        int s = src[tile0 + j];
        int b = d >> 9;
        u32 p = atomicAdd(&hoff[b], 1u);
        stage[p] = ((u32)s << 9) | (u32)(d & 511);
        bkt[p] = (unsigned char)b;
    }
    __syncthreads();
    for (int j = t; j < cntE; j += 256){
        int b = bkt[j];
        pairs[gbase[b] + (int)((u32)j - hexcl[b])] = stage[j];
    }
}

__global__ __launch_bounds__(256) void sort2_kernel(const u32* __restrict__ pairs,
                                                    const int* __restrict__ bbase,
                                                    int* __restrict__ indptr,
                                                    float* __restrict__ invdeg,
                                                    int* __restrict__ esrc,
                                                    int M, int E, int nbuk){
    __shared__ int ndeg[512];
    __shared__ int cur[512];
    __shared__ int wsI[4];
    const int b = blockIdx.x;
    const int node0 = b * 512;
    const int lo = bbase[b];
    const int hi = (b + 1 < nbuk) ? bbase[b + 1] : E;
    const int t = threadIdx.x, lane = t & 63, wv = t >> 6;

    ndeg[t] = 0; ndeg[t + 256] = 0;
    __syncthreads();
    for (int i = lo + t; i < hi; i += 256) atomicAdd(&ndeg[pairs[i] & 511], 1);
    __syncthreads();

    const int d0 = ndeg[2*t], d1 = ndeg[2*t + 1];
    const int p = d0 + d1;
    int s = p;
    for (int off = 1; off < 64; off <<= 1){
        int n = __shfl_up(s, off);
        if (lane >= off) s += n;
    }
    if (lane == 63) wsI[wv] = s;
    __syncthreads();
    int woff = 0;
    for (int w = 0; w < wv; ++w) woff += wsI[w];
    const int incl = s + woff;
    const int excl0 = incl - p;
    const int excl1 = excl0 + d0;

    const int n0 = node0 + 2*t, n1 = node0 + 2*t + 1;
    if (n0 < M){
        indptr[n0 + 1] = lo + excl0 + d0;
        invdeg[n0] = 1.0f / (float)max(d0, 1);
        cur[2*t] = lo + excl0;
    }
    if (n1 < M){
        indptr[n1 + 1] = lo + excl1 + d1;
        invdeg[n1] = 1.0f / (float)max(d1, 1);
        cur[2*t + 1] = lo + excl1;
    }
    if (b == 0 && t == 0) indptr[0] = 0;
    __syncthreads();
    for (int i = lo + t; i < hi; i += 256){
        u32 v = pairs[i];
        int pos = atomicAdd(&cur[v & 511], 1);
        esrc[pos] = (int)(v >> 9);
    }
}

// ------- weight packing -------

__global__ void pack_kernel(const float* __restrict__ wself, const float* __restrict__ wneigh,
                            u16* __restrict__ bp, int N){
    int i = blockIdx.x * 256 + threadIdx.x;
    if (i >= N * 256) return;
    int n = i >> 8, k = i & 255;
    float v = (k < 128) ? wself[k * N + n] : wneigh[(k - 128) * N + n];
    bp[i] = f2bf(v);
}

// ------- FUSED layer: agg (gather+mean, opt affine+ReLU) -> MFMA GEMM -> bias (+BN stats) -------
// One block = one 16-row tile. Phase 1: 4 waves x 4 nodes gather into LDS.
// Phase 2: per-wave column slice (NTW*16 cols), B pinned in regs, K=256 MFMA.

template<int NTW, bool STATS, bool AFF>
__global__ __launch_bounds__(256) void fused_kernel(const u16* __restrict__ h,
                                                    const int* __restrict__ indptr,
                                                    const int* __restrict__ esrc,
                                                    const float* __restrict__ invdeg,
                                                    const u16* __restrict__ Bp,
                                                    const float* __restrict__ bias,
                                                    const float* __restrict__ cs,
                                                    void* __restrict__ outPre,
                                                    float* __restrict__ partials, int M){
    constexpr int N = NTW * 64;          // 4 waves x NTW*16 cols
    constexpr int ROWP = 130;            // aggLds row pitch (u16), pad vs bank conflicts
    __shared__ u16 aggLds[16][ROWP];
    __shared__ float s_sc[128], s_sh[128];
    const int wave = threadIdx.x >> 6;
    const int lane = threadIdx.x & 63;
    const int m15 = lane & 15;
    const int quad = lane >> 4;
    const int g    = lane >> 4;          // edge subgroup in gather phase
    const int l16  = lane & 15;          // channel-chunk in gather phase
    const int colbase = wave * (NTW * 16);
    const int t = blockIdx.x;            // tile index

    if (AFF && threadIdx.x < 128){
        s_sc[threadIdx.x] = cs[256 + threadIdx.x];
        s_sh[threadIdx.x] = cs[384 + threadIdx.x];
    }

    // issue self-row loads early (independent of gather)
    short8 Aself[4];
    {
        int arow = min(t * 16 + m15, M - 1);
        const u16* p0 = h + (size_t)arow * 128 + quad * 8;
        #pragma unroll
        for (int k0 = 0; k0 < 4; ++k0) Aself[k0] = *(const short8*)(p0 + k0 * 32);
    }

    // pin B fragments + bias
    short8 breg[NTW][8];
    float bv[NTW];
    #pragma unroll
    for (int nt = 0; nt < NTW; ++nt){
        bv[nt] = bias[colbase + nt * 16 + m15];
        #pragma unroll
        for (int k0 = 0; k0 < 8; ++k0)
            breg[nt][k0] = *(const short8*)(Bp + (size_t)(colbase + nt * 16 + m15) * 256 + k0 * 32 + quad * 8);
    }

    // gather-phase affine coefficients (channel = l16*8 + j)
    floatx2 scv[4], shv[4];
    if (AFF){
        #pragma unroll
        for (int j = 0; j < 4; ++j){
            scv[j].x = cs[256 + l16 * 8 + 2*j];
            scv[j].y = cs[256 + l16 * 8 + 2*j + 1];
            shv[j].x = cs[384 + l16 * 8 + 2*j];
            shv[j].y = cs[384 + l16 * 8 + 2*j + 1];
        }
    }

    // ---- phase 1: aggregate 4 nodes per wave into LDS ----
    #pragma unroll
    for (int i = 0; i < 4; ++i){
        const int n = t * 16 + wave * 4 + i;
        const int nn = min(n, M - 1);
        const int beg = indptr[nn], end = indptr[nn + 1];
        floatx2 acc[4];
        #pragma unroll
        for (int j = 0; j < 4; ++j){ acc[j].x = 0.f; acc[j].y = 0.f; }

        #pragma unroll 2
        for (int e0 = beg; e0 < end; e0 += 4){
            int e = e0 + g;
            if (e < end){
                int idx = esrc[e];
                uint4 v = *(const uint4*)(h + (size_t)idx * 128 + l16 * 8);
                u32 w[4] = {v.x, v.y, v.z, v.w};
                #pragma unroll
                for (int j = 0; j < 4; ++j){
                    floatx2 tt;
                    tt.x = bits2f(w[j] << 16);
                    tt.y = bits2f(w[j] & 0xffff0000u);
                    if (AFF){
                        tt = tt * scv[j] + shv[j];
                        tt.x = fmaxf(tt.x, 0.f);
                        tt.y = fmaxf(tt.y, 0.f);
                    }
                    acc[j] += tt;
                }
            }
        }

        float s[8];
        #pragma unroll
        for (int j = 0; j < 4; ++j){ s[2*j] = acc[j].x; s[2*j+1] = acc[j].y; }
        #pragma unroll
        for (int k = 0; k < 8; ++k){
            s[k] += __shfl_xor(s[k], 16);
            s[k] += __shfl_xor(s[k], 32);
        }
        if (g == 0){
            float fs = invdeg[nn];
            uint4 o;
            o.x = (u32)f2bf(s[0] * fs) | ((u32)f2bf(s[1] * fs) << 16);
            o.y = (u32)f2bf(s[2] * fs) | ((u32)f2bf(s[3] * fs) << 16);
            o.z = (u32)f2bf(s[4] * fs) | ((u32)f2bf(s[5] * fs) << 16);
            o.w = (u32)f2bf(s[6] * fs) | ((u32)f2bf(s[7] * fs) << 16);
            *(uint4*)&aggLds[wave * 4 + i][l16 * 8] = o;
        }
    }
    __syncthreads();

    // ---- phase 2: A fragments, affine on self rows, MFMA, epilogue ----
    if (AFF){
        #pragma unroll
        for (int k0 = 0; k0 < 4; ++k0){
            const int cb = k0 * 32 + quad * 8;
            short8 raw = Aself[k0];
            #pragma unroll
            for (int j = 0; j < 8; ++j){
                float f = bits2f(((u32)(u16)raw[j]) << 16);
                f = fmaxf(fmaf(f, s_sc[cb + j], s_sh[cb + j]), 0.f);
                raw[j] = (short)f2bf(f);
            }
            Aself[k0] = raw;
        }
    }
    short8 Aagg[4];
    #pragma unroll
    for (int k0 = 0; k0 < 4; ++k0)
        Aagg[k0] = *(const short8*)&aggLds[m15][k0 * 32 + quad * 8];

    floatx4 acc[NTW];
    #pragma unroll
    for (int nt = 0; nt < NTW; ++nt) acc[nt] = 0.0f;
    #pragma unroll
    for (int k0 = 0; k0 < 4; ++k0)
        #pragma unroll
        for (int nt = 0; nt < NTW; ++nt)
            acc[nt] = __builtin_amdgcn_mfma_f32_16x16x32_bf16(Aself[k0], breg[nt][k0], acc[nt], 0, 0, 0);
    #pragma unroll
    for (int k0 = 0; k0 < 4; ++k0)
        #pragma unroll
        for (int nt = 0; nt < NTW; ++nt)
            acc[nt] = __builtin_amdgcn_mfma_f32_16x16x32_bf16(Aagg[k0], breg[nt][4 + k0], acc[nt], 0, 0, 0);

    const int row0 = t * 16 + quad * 4;
    #pragma unroll
    for (int nt = 0; nt < NTW; ++nt){
        const int col = colbase + nt * 16 + m15;
        float s = 0.f, q = 0.f;
        #pragma unroll
        for (int r = 0; r < 4; ++r){
            int row = row0 + r;
            if (row < M){
                float v = acc[nt][r] + bv[nt];
                if (STATS){
                    ((u16*)outPre)[(size_t)row * N + col] = f2bf(v);
                    s += v;
                    q = fmaf(v, v, q);
                } else {
                    ((float*)outPre)[(size_t)row * N + col] = v;
                }
            }
        }
        if (STATS){
            s += __shfl_xor(s, 16);  s += __shfl_xor(s, 32);
            q += __shfl_xor(q, 16);  q += __shfl_xor(q, 32);
            if (lane < 16){
                partials[(size_t)t * (2 * N) + col]     = s;
                partials[(size_t)t * (2 * N) + N + col] = q;
            }
        }
    }
}

// ---------------- BN: reduce block partials; finalize scale/shift ----------------

__global__ __launch_bounds__(256) void bnred_kernel(const float* __restrict__ partials,
                                                    float* __restrict__ cs, int nblk){
    const int t = threadIdx.x;
    float s = 0.f;
    for (int b = blockIdx.x; b < nblk; b += (int)gridDim.x)
        s += partials[(size_t)b * 256 + t];
    atomicAdd(&cs[t], s);
}

__global__ void bnfin_kernel(float* __restrict__ cs, const float* __restrict__ gamma,
                             const float* __restrict__ beta, float invM){
    int c = threadIdx.x;  // 128
    float mu  = cs[c] * invM;
    float var = fmaxf(cs[128 + c] * invM - mu * mu, 0.0f);
    float sc  = gamma[c] * rsqrtf(var + 1e-5f);
    cs[256 + c] = sc;
    cs[384 + c] = beta[c] - mu * sc;
}

// ---------------- log_softmax (one wave per 64-wide row) ----------------

__global__ __launch_bounds__(256) void lsm_kernel(const float* __restrict__ pre,
                                                  float* __restrict__ out, int M){
    const int wave = threadIdx.x >> 6;
    const int lane = threadIdx.x & 63;
    const int row = blockIdx.x * 4 + wave;
    if (row >= M) return;
    float v = pre[(size_t)row * 64 + lane];
    float m = v;
    #pragma unroll
    for (int o = 32; o; o >>= 1) m = fmaxf(m, __shfl_xor(m, o));
    float e = __expf(v - m);
    float s = e;
    #pragma unroll
    for (int o = 32; o; o >>= 1) s += __shfl_xor(s, o);
    out[(size_t)row * 64 + lane] = v - m - __logf(s);
}

// ---------------- host ----------------

extern "C" void kernel_launch(void* const* d_in, const int* in_sizes, int n_in,
                              void* d_out, int out_size, void* d_ws, size_t ws_size,
                              hipStream_t stream) {
    const float* x   = (const float*)d_in[0];
    const int*   src = (const int*)d_in[1];
    const int*   dst = (const int*)d_in[2];
    const float* wself[3]  = {(const float*)d_in[3], (const float*)d_in[6], (const float*)d_in[9]};
    const float* wneigh[3] = {(const float*)d_in[4], (const float*)d_in[7], (const float*)d_in[10]};
    const float* bias[3]   = {(const float*)d_in[5], (const float*)d_in[8], (const float*)d_in[11]};
    const float* gamma[2]  = {(const float*)d_in[12], (const float*)d_in[14]};
    const float* beta[2]   = {(const float*)d_in[13], (const float*)d_in[15]};

    const int M = in_sizes[0] / 128;   // 100000
    const int E = in_sizes[1];         // 1600000
    const int NBUK = (M + 511) / 512;  // 196
    const int T = (M + 15) / 16;       // 6250 tiles

    char* ws = (char*)d_ws;
    size_t off = 0;
    auto alloc = [&](size_t bytes) -> void* {
        void* p = ws + off;
        off = (off + bytes + 511) & ~(size_t)511;
        return p;
    };
    int*   gbcnt  = (int*)alloc(256 * 4);
    int*   bbase  = (int*)alloc(256 * 4);
    int*   bcur   = (int*)alloc(256 * 4);
    int*   indptr = (int*)alloc((size_t)(M + 1) * 4);
    u32*   pairs  = (u32*)alloc((size_t)E * 4);
    int*   esrc   = (int*)alloc((size_t)E * 4);
    float* invdeg = (float*)alloc((size_t)M * 4);
    u16* bpack0 = (u16*)alloc(128 * 256 * 2);
    u16* bpack1 = (u16*)alloc(128 * 256 * 2);
    u16* bpack2 = (u16*)alloc(64 * 256 * 2);
    float* colstat0 = (float*)alloc(512 * 4);
    float* colstat1 = (float*)alloc(512 * 4);
    float* partials = (float*)alloc((size_t)T * 256 * 4);
    u16*   hbuf   = (u16*)alloc((size_t)M * 128 * 2);   // bf16(x)
    u16*   preA   = (u16*)alloc((size_t)M * 128 * 2);   // layer0 pre-BN (bf16)
    u16*   preB   = (u16*)alloc((size_t)M * 128 * 2);   // layer1 pre-BN (bf16)
    float* preF   = (float*)alloc((size_t)M * 64 * 4);  // final logits (f32)

    // --- CSR build ---
    hipMemsetAsync(gbcnt, 0, 256 * 4, stream);
    bhist_kernel<<<(E + 8191) / 8192, 256, 0, stream>>>(dst, gbcnt, E);
    bscan_kernel<<<1, 256, 0, stream>>>(gbcnt, bbase, bcur, NBUK);
    bin_kernel<<<(E + BIN_TILE - 1) / BIN_TILE, 256, 0, stream>>>(src, dst, bcur, pairs, E, NBUK);
    sort2_kernel<<<NBUK, 256, 0, stream>>>(pairs, bbase, indptr, invdeg, esrc, M, E, NBUK);

    // --- bf16 convert + weight pack ---
    cvt_kernel<<<((M * 32) + 255) / 256, 256, 0, stream>>>(x, hbuf, M * 32);
    pack_kernel<<<(128 * 256 + 255) / 256, 256, 0, stream>>>(wself[0], wneigh[0], bpack0, 128);
    pack_kernel<<<(128 * 256 + 255) / 256, 256, 0, stream>>>(wself[1], wneigh[1], bpack1, 128);
    pack_kernel<<<(64 * 256 + 255) / 256, 256, 0, stream>>>(wself[2], wneigh[2], bpack2, 64);

    // --- layer 0 (no input affine) ---
    fused_kernel<2, true, false><<<T, 256, 0, stream>>>(hbuf, indptr, esrc, invdeg,
                                                        bpack0, bias[0], nullptr, preA, partials, M);
    hipMemsetAsync(colstat0, 0, 256 * 4, stream);
    bnred_kernel<<<32, 256, 0, stream>>>(partials, colstat0, T);
    bnfin_kernel<<<1, 128, 0, stream>>>(colstat0, gamma[0], beta[0], 1.0f / (float)M);

    // --- layer 1 ---
    fused_kernel<2, true, true><<<T, 256, 0, stream>>>(preA, indptr, esrc, invdeg,
                                                       bpack1, bias[1], colstat0, preB, partials, M);
    hipMemsetAsync(colstat1, 0, 256 * 4, stream);
    bnred_kernel<<<32, 256, 0, stream>>>(partials, colstat1, T);
    bnfin_kernel<<<1, 128, 0, stream>>>(colstat1, gamma[1], beta[1], 1.0f / (float)M);

    // --- layer 2 (N=64, f32 out, no stats) ---
    fused_kernel<1, false, true><<<T, 256, 0, stream>>>(preB, indptr, esrc, invdeg,
                                                        bpack2, bias[2], colstat1, preF, partials, M);
    lsm_kernel<<<(M + 3) / 4, 256, 0, stream>>>(preF, (float*)d_out, M);
}

// Round 12
// 532.919 us; speedup vs baseline: 1.5526x; 1.5526x over previous
//
#include <hip/hip_runtime.h>
#include <hip/hip_bf16.h>

typedef unsigned short u16;
typedef unsigned char  u8;
typedef unsigned int   u32;
typedef __attribute__((ext_vector_type(8))) short short8;
typedef __attribute__((ext_vector_type(4))) float floatx4;
typedef __attribute__((ext_vector_type(2))) float floatx2;

__device__ __forceinline__ float bits2f(u32 v){ float f; __builtin_memcpy(&f, &v, 4); return f; }
__device__ __forceinline__ u16 f2bf(float f){
    __hip_bfloat16 h = __float2bfloat16(f);
    u16 u; __builtin_memcpy(&u, &h, 2); return u;
}

// ---------------- f32 -> bf16 + fp8 conversion (x into hbuf, x8) ----------------

__global__ __launch_bounds__(256) void cvt_kernel(const float* __restrict__ in,
                                                  u16* __restrict__ out,
                                                  u32* __restrict__ out8, int total4){
    int i = blockIdx.x * 256 + threadIdx.x;   // 4 floats per thread
    if (i >= total4) return;
    float4 v = ((const float4*)in)[i];
    uint2 o;
    o.x = (u32)f2bf(v.x) | ((u32)f2bf(v.y) << 16);
    o.y = (u32)f2bf(v.z) | ((u32)f2bf(v.w) << 16);
    ((uint2*)out)[i] = o;
    u32 p8 = (u32)__builtin_amdgcn_cvt_pk_fp8_f32(v.x, v.y, 0, false);
    p8     = (u32)__builtin_amdgcn_cvt_pk_fp8_f32(v.z, v.w, (int)p8, true);
    out8[i] = p8;
}

// ---------------- bf16 -> fp8 copy (pre -> pre8) ----------------

__global__ __launch_bounds__(256) void cvt8_kernel(const u16* __restrict__ in,
                                                   uint2* __restrict__ out8, int total8){
    int i = blockIdx.x * 256 + threadIdx.x;   // 8 bf16 per thread
    if (i >= total8) return;
    uint4 v = ((const uint4*)in)[i];
    float f0 = bits2f(v.x << 16), f1 = bits2f(v.x & 0xffff0000u);
    float f2 = bits2f(v.y << 16), f3 = bits2f(v.y & 0xffff0000u);
    float f4 = bits2f(v.z << 16), f5 = bits2f(v.z & 0xffff0000u);
    float f6 = bits2f(v.w << 16), f7 = bits2f(v.w & 0xffff0000u);
    u32 lo = (u32)__builtin_amdgcn_cvt_pk_fp8_f32(f0, f1, 0, false);
    lo     = (u32)__builtin_amdgcn_cvt_pk_fp8_f32(f2, f3, (int)lo, true);
    u32 hi = (u32)__builtin_amdgcn_cvt_pk_fp8_f32(f4, f5, 0, false);
    hi     = (u32)__builtin_amdgcn_cvt_pk_fp8_f32(f6, f7, (int)hi, true);
    uint2 o; o.x = lo; o.y = hi;
    out8[i] = o;
}

// ---------------- CSR build: bucket hist -> bucket scan -> multisplit bin -> bucket sort ----------------

__global__ __launch_bounds__(256) void bhist_kernel(const int* __restrict__ dst,
                                                    int* __restrict__ gbcnt, int E){
    __shared__ int bc[256];
    const int t = threadIdx.x;
    bc[t] = 0;
    __syncthreads();
    const int tile0 = blockIdx.x * 8192;
    const int cnt = min(8192, E - tile0);
    for (int j = t; j < cnt; j += 256) atomicAdd(&bc[dst[tile0 + j] >> 9], 1);
    __syncthreads();
    if (bc[t] > 0) atomicAdd(&gbcnt[t], bc[t]);
}

__global__ __launch_bounds__(256) void bscan_kernel(const int* __restrict__ gbcnt,
                                                    int* __restrict__ bbase,
                                                    int* __restrict__ bcur, int nbuk){
    __shared__ int ws[4];
    const int t = threadIdx.x, lane = t & 63, wv = t >> 6;
    int v = (t < nbuk) ? gbcnt[t] : 0;
    int s = v;
    for (int off = 1; off < 64; off <<= 1){
        int n = __shfl_up(s, off);
        if (lane >= off) s += n;
    }
    if (lane == 63) ws[wv] = s;
    __syncthreads();
    int woff = 0;
    for (int w = 0; w < wv; ++w) woff += ws[w];
    int excl = s + woff - v;
    if (t < nbuk){ bbase[t] = excl; bcur[t] = excl; }
}

#define BIN_TILE 8192
__global__ __launch_bounds__(256) void bin_kernel(const int* __restrict__ src,
                                                  const int* __restrict__ dst,
                                                  int* __restrict__ bcur,
                                                  u32* __restrict__ pairs, int E, int nbuk){
    __shared__ u32 hcnt[256], hexcl[256], hoff[256];
    __shared__ int gbase[256];
    __shared__ u32 stage[BIN_TILE];
    __shared__ unsigned char bkt[BIN_TILE];
    const int t = threadIdx.x;
    const int tile0 = blockIdx.x * BIN_TILE;
    const int cntE = min(BIN_TILE, E - tile0);

    hcnt[t] = 0;
    __syncthreads();
    for (int j = t; j < cntE; j += 256){
        int d = dst[tile0 + j];
        atomicAdd(&hcnt[d >> 9], 1u);
    }
    __syncthreads();
    if (t < 64){
        u32 a0 = hcnt[4*t], a1 = hcnt[4*t+1], a2 = hcnt[4*t+2], a3 = hcnt[4*t+3];
        u32 lsum = a0 + a1 + a2 + a3;
        u32 s = lsum;
        for (int off = 1; off < 64; off <<= 1){
            u32 n = __shfl_up(s, off);
            if (t >= off) s += n;
        }
        u32 base = s - lsum;
        hexcl[4*t]   = base;
        hexcl[4*t+1] = base + a0;
        hexcl[4*t+2] = base + a0 + a1;
        hexcl[4*t+3] = base + a0 + a1 + a2;
        hoff[4*t]   = base;
        hoff[4*t+1] = base + a0;
        hoff[4*t+2] = base + a0 + a1;
        hoff[4*t+3] = base + a0 + a1 + a2;
    }
    __syncthreads();
    if (t < nbuk && hcnt[t] > 0) gbase[t] = atomicAdd(&bcur[t], (int)hcnt[t]);
    for (int j = t; j < cntE; j += 256){
        int d = dst[tile0 + j];
        int s = src[tile0 + j];
        int b = d >> 9;
        u32 p = atomicAdd(&hoff[b], 1u);
        stage[p] = ((u32)s << 9) | (u32)(d & 511);
        bkt[p] = (unsigned char)b;
    }
    __syncthreads();
    for (int j = t; j < cntE; j += 256){
        int b = bkt[j];
        pairs[gbase[b] + (int)((u32)j - hexcl[b])] = stage[j];
    }
}

__global__ __launch_bounds__(256) void sort2_kernel(const u32* __restrict__ pairs,
                                                    const int* __restrict__ bbase,
                                                    int* __restrict__ indptr,
                                                    float* __restrict__ invdeg,
                                                    int* __restrict__ esrc,
                                                    int M, int E, int nbuk){
    __shared__ int ndeg[512];
    __shared__ int cur[512];
    __shared__ int wsI[4];
    const int b = blockIdx.x;
    const int node0 = b * 512;
    const int lo = bbase[b];
    const int hi = (b + 1 < nbuk) ? bbase[b + 1] : E;
    const int t = threadIdx.x, lane = t & 63, wv = t >> 6;

    ndeg[t] = 0; ndeg[t + 256] = 0;
    __syncthreads();
    for (int i = lo + t; i < hi; i += 256) atomicAdd(&ndeg[pairs[i] & 511], 1);
    __syncthreads();

    const int d0 = ndeg[2*t], d1 = ndeg[2*t + 1];
    const int p = d0 + d1;
    int s = p;
    for (int off = 1; off < 64; off <<= 1){
        int n = __shfl_up(s, off);
        if (lane >= off) s += n;
    }
    if (lane == 63) wsI[wv] = s;
    __syncthreads();
    int woff = 0;
    for (int w = 0; w < wv; ++w) woff += wsI[w];
    const int incl = s + woff;
    const int excl0 = incl - p;
    const int excl1 = excl0 + d0;

    const int n0 = node0 + 2*t, n1 = node0 + 2*t + 1;
    if (n0 < M){
        indptr[n0 + 1] = lo + excl0 + d0;
        invdeg[n0] = 1.0f / (float)max(d0, 1);
        cur[2*t] = lo + excl0;
    }
    if (n1 < M){
        indptr[n1 + 1] = lo + excl1 + d1;
        invdeg[n1] = 1.0f / (float)max(d1, 1);
        cur[2*t + 1] = lo + excl1;
    }
    if (b == 0 && t == 0) indptr[0] = 0;
    __syncthreads();
    for (int i = lo + t; i < hi; i += 256){
        u32 v = pairs[i];
        int pos = atomicAdd(&cur[v & 511], 1);
        esrc[pos] = (int)(v >> 9);
    }
}

// ------- weight packing -------

__global__ void pack_kernel(const float* __restrict__ wself, const float* __restrict__ wneigh,
                            u16* __restrict__ bp, int N){
    int i = blockIdx.x * 256 + threadIdx.x;
    if (i >= N * 256) return;
    int n = i >> 8, k = i & 255;
    float v = (k < 128) ? wself[k * N + n] : wneigh[(k - 128) * N + n];
    bp[i] = f2bf(v);
}

// ---------------- aggregation over fp8 table (packed-f32 accumulate, opt fused affine+ReLU) -------
// gathers 128-B fp8 rows; dequant via v_cvt_pk_f32_fp8; mean written bf16.

template<bool AFF>
__global__ __launch_bounds__(256) void agg_kernel(const u8* __restrict__ h8,
                                                  const int* __restrict__ indptr,
                                                  const int* __restrict__ esrc,
                                                  const float* __restrict__ invdeg,
                                                  const float* __restrict__ cs,
                                                  u16* __restrict__ agg, int M){
    const int wave = threadIdx.x >> 6;
    const int lane = threadIdx.x & 63;
    const int g    = lane >> 4;
    const int l16  = lane & 15;
    const int n = blockIdx.x * 4 + wave;
    if (n >= M) return;

    floatx2 scv[4], shv[4];
    if (AFF){
        #pragma unroll
        for (int j = 0; j < 4; ++j){
            scv[j].x = cs[256 + l16 * 8 + 2*j];
            scv[j].y = cs[256 + l16 * 8 + 2*j + 1];
            shv[j].x = cs[384 + l16 * 8 + 2*j];
            shv[j].y = cs[384 + l16 * 8 + 2*j + 1];
        }
    }

    const int beg = indptr[n], end = indptr[n + 1];
    floatx2 acc[4];
    #pragma unroll
    for (int i = 0; i < 4; ++i){ acc[i].x = 0.f; acc[i].y = 0.f; }

    #pragma unroll 2
    for (int e0 = beg; e0 < end; e0 += 16){
        uint2 v[4];
        #pragma unroll
        for (int u = 0; u < 4; ++u){
            int e = e0 + u * 4 + g;
            if (e < end){
                int idx = esrc[e];
                v[u] = *(const uint2*)(h8 + (size_t)idx * 128 + l16 * 8);
            }
        }
        #pragma unroll
        for (int u = 0; u < 4; ++u){
            int e = e0 + u * 4 + g;
            if (e < end){
                floatx2 t0 = __builtin_amdgcn_cvt_pk_f32_fp8(v[u].x, false);
                floatx2 t1 = __builtin_amdgcn_cvt_pk_f32_fp8(v[u].x, true);
                floatx2 t2 = __builtin_amdgcn_cvt_pk_f32_fp8(v[u].y, false);
                floatx2 t3 = __builtin_amdgcn_cvt_pk_f32_fp8(v[u].y, true);
                if (AFF){
                    t0 = t0 * scv[0] + shv[0];
                    t1 = t1 * scv[1] + shv[1];
                    t2 = t2 * scv[2] + shv[2];
                    t3 = t3 * scv[3] + shv[3];
                    t0.x = fmaxf(t0.x, 0.f); t0.y = fmaxf(t0.y, 0.f);
                    t1.x = fmaxf(t1.x, 0.f); t1.y = fmaxf(t1.y, 0.f);
                    t2.x = fmaxf(t2.x, 0.f); t2.y = fmaxf(t2.y, 0.f);
                    t3.x = fmaxf(t3.x, 0.f); t3.y = fmaxf(t3.y, 0.f);
                }
                acc[0] += t0; acc[1] += t1; acc[2] += t2; acc[3] += t3;
            }
        }
    }

    float s[8];
    #pragma unroll
    for (int j = 0; j < 4; ++j){ s[2*j] = acc[j].x; s[2*j+1] = acc[j].y; }
    #pragma unroll
    for (int i = 0; i < 8; ++i){
        s[i] += __shfl_xor(s[i], 16);
        s[i] += __shfl_xor(s[i], 32);
    }

    if (g == 0){
        float fs = invdeg[n];
        uint4 o;
        o.x = (u32)f2bf(s[0] * fs) | ((u32)f2bf(s[1] * fs) << 16);
        o.y = (u32)f2bf(s[2] * fs) | ((u32)f2bf(s[3] * fs) << 16);
        o.z = (u32)f2bf(s[4] * fs) | ((u32)f2bf(s[5] * fs) << 16);
        o.w = (u32)f2bf(s[6] * fs) | ((u32)f2bf(s[7] * fs) << 16);
        *(uint4*)(agg + (size_t)n * 128 + l16 * 8) = o;
    }
}

// ------- GEMM: B pinned in registers, A streamed (ping-pong), fused bias + BN stats -------

template<int NTW, bool STATS, bool AFFA>
__global__ __launch_bounds__(256, 2) void gemm2_kernel(const u16* __restrict__ hA,
                                                       const u16* __restrict__ aggA,
                                                       const u16* __restrict__ Bp,
                                                       const float* __restrict__ bias,
                                                       const float* __restrict__ cs,
                                                       void* __restrict__ outPre,
                                                       float* __restrict__ partials,
                                                       int M, int T, int nstream){
    constexpr int N = NTW * 32;
    __shared__ float sbuf[4][N], s2buf[4][N];
    __shared__ float s_sc[128], s_sh[128];
    const int wave = threadIdx.x >> 6;
    const int lane = threadIdx.x & 63;
    const int m15 = lane & 15;
    const int quad = lane >> 4;
    const int colbase = (wave & 1) * (NTW * 16);

    if (STATS){
        for (int i = threadIdx.x; i < 4 * N; i += 256){
            ((float*)sbuf)[i] = 0.f;
            ((float*)s2buf)[i] = 0.f;
        }
    }
    if (AFFA && threadIdx.x < 128){
        s_sc[threadIdx.x] = cs[256 + threadIdx.x];
        s_sh[threadIdx.x] = cs[384 + threadIdx.x];
    }
    if (STATS || AFFA) __syncthreads();

    short8 breg[NTW][8];
    float bv[NTW];
    #pragma unroll
    for (int nt = 0; nt < NTW; ++nt){
        bv[nt] = bias[colbase + nt * 16 + m15];
        #pragma unroll
        for (int k0 = 0; k0 < 8; ++k0)
            breg[nt][k0] = *(const short8*)(Bp + (size_t)(colbase + nt * 16 + m15) * 256 + k0 * 32 + quad * 8);
    }

    float sS[NTW], sQ[NTW];
    #pragma unroll
    for (int nt = 0; nt < NTW; ++nt){ sS[nt] = 0.f; sQ[nt] = 0.f; }

    auto loadA = [&](short8* buf, int tile){
        int arow = tile * 16 + m15;
        if (arow >= M) arow = M - 1;
        const u16* p0 = hA   + (size_t)arow * 128 + quad * 8;
        const u16* p1 = aggA + (size_t)arow * 128 + quad * 8;
        #pragma unroll
        for (int k0 = 0; k0 < 4; ++k0) buf[k0]     = *(const short8*)(p0 + k0 * 32);
        #pragma unroll
        for (int k0 = 0; k0 < 4; ++k0) buf[4 + k0] = *(const short8*)(p1 + k0 * 32);
    };

    auto compute = [&](short8* buf, int tile){
        if (AFFA){
            #pragma unroll
            for (int k0 = 0; k0 < 4; ++k0){
                const int cb = k0 * 32 + quad * 8;
                short8 raw = buf[k0];
                #pragma unroll
                for (int j = 0; j < 8; ++j){
                    float f = bits2f(((u32)(u16)raw[j]) << 16);
                    f = fmaxf(fmaf(f, s_sc[cb + j], s_sh[cb + j]), 0.f);
                    raw[j] = (short)f2bf(f);
                }
                buf[k0] = raw;
            }
        }
        floatx4 acc[NTW];
        #pragma unroll
        for (int nt = 0; nt < NTW; ++nt) acc[nt] = 0.0f;
        #pragma unroll
        for (int k0 = 0; k0 < 8; ++k0)
            #pragma unroll
            for (int nt = 0; nt < NTW; ++nt)
                acc[nt] = __builtin_amdgcn_mfma_f32_16x16x32_bf16(buf[k0], breg[nt][k0], acc[nt], 0, 0, 0);
        const int row0 = tile * 16 + quad * 4;
        #pragma unroll
        for (int nt = 0; nt < NTW; ++nt){
            const int col = colbase + nt * 16 + m15;
            #pragma unroll
            for (int r = 0; r < 4; ++r){
                int row = row0 + r;
                if (row < M){
                    float v = acc[nt][r] + bv[nt];
                    if (STATS){
                        ((u16*)outPre)[(size_t)row * N + col] = f2bf(v);
                        sS[nt] += v;
                        sQ[nt] = fmaf(v, v, sQ[nt]);
                    } else {
                        ((float*)outPre)[(size_t)row * N + col] = v;
                    }
                }
            }
        }
    };

    short8 A0[8], A1[8];
    int t = blockIdx.x * 2 + (wave >> 1);
    const int stride = nstream;
    if (t < T){
        loadA(A0, t);
        while (true){
            int tn = t + stride;
            if (tn < T) loadA(A1, tn);
            compute(A0, t);
            t = tn;
            if (t >= T) break;
            tn = t + stride;
            if (tn < T) loadA(A0, tn);
            compute(A1, t);
            t = tn;
            if (t >= T) break;
        }
    }

    if (STATS){
        #pragma unroll
        for (int nt = 0; nt < NTW; ++nt){
            float s = sS[nt], q = sQ[nt];
            s += __shfl_xor(s, 16);  s += __shfl_xor(s, 32);
            q += __shfl_xor(q, 16);  q += __shfl_xor(q, 32);
            if (lane < 16){
                sbuf[wave][colbase + nt * 16 + m15] = s;
                s2buf[wave][colbase + nt * 16 + m15] = q;
            }
        }
        __syncthreads();
        const int c = threadIdx.x;
        if (c < N){
            float S  = sbuf[0][c] + sbuf[1][c] + sbuf[2][c] + sbuf[3][c];
            float S2 = s2buf[0][c] + s2buf[1][c] + s2buf[2][c] + s2buf[3][c];
            partials[(size_t)blockIdx.x * (2 * N) + c]     = S;
            partials[(size_t)blockIdx.x * (2 * N) + N + c] = S2;
        }
    }
}

// ---------------- BN: reduce block partials; finalize scale/shift ----------------

__global__ __launch_bounds__(256) void bnred_kernel(const float* __restrict__ partials,
                                                    float* __restrict__ cs, int nblk){
    const int t = threadIdx.x;
    float s = 0.f;
    for (int b = blockIdx.x; b < nblk; b += (int)gridDim.x)
        s += partials[(size_t)b * 256 + t];
    atomicAdd(&cs[t], s);
}

__global__ void bnfin_kernel(float* __restrict__ cs, const float* __restrict__ gamma,
                             const float* __restrict__ beta, float invM){
    int c = threadIdx.x;  // 128
    float mu  = cs[c] * invM;
    float var = fmaxf(cs[128 + c] * invM - mu * mu, 0.0f);
    float sc  = gamma[c] * rsqrtf(var + 1e-5f);
    cs[256 + c] = sc;
    cs[384 + c] = beta[c] - mu * sc;
}

// ---------------- log_softmax (one wave per 64-wide row) ----------------

__global__ __launch_bounds__(256) void lsm_kernel(const float* __restrict__ pre,
                                                  float* __restrict__ out, int M){
    const int wave = threadIdx.x >> 6;
    const int lane = threadIdx.x & 63;
    const int row = blockIdx.x * 4 + wave;
    if (row >= M) return;
    float v = pre[(size_t)row * 64 + lane];
    float m = v;
    #pragma unroll
    for (int o = 32; o; o >>= 1) m = fmaxf(m, __shfl_xor(m, o));
    float e = __expf(v - m);
    float s = e;
    #pragma unroll
    for (int o = 32; o; o >>= 1) s += __shfl_xor(s, o);
    out[(size_t)row * 64 + lane] = v - m - __logf(s);
}

// ---------------- host ----------------

extern "C" void kernel_launch(void* const* d_in, const int* in_sizes, int n_in,
                              void* d_out, int out_size, void* d_ws, size_t ws_size,
                              hipStream_t stream) {
    const float* x   = (const float*)d_in[0];
    const int*   src = (const int*)d_in[1];
    const int*   dst = (const int*)d_in[2];
    const float* wself[3]  = {(const float*)d_in[3], (const float*)d_in[6], (const float*)d_in[9]};
    const float* wneigh[3] = {(const float*)d_in[4], (const float*)d_in[7], (const float*)d_in[10]};
    const float* bias[3]   = {(const float*)d_in[5], (const float*)d_in[8], (const float*)d_in[11]};
    const float* gamma[2]  = {(const float*)d_in[12], (const float*)d_in[14]};
    const float* beta[2]   = {(const float*)d_in[13], (const float*)d_in[15]};

    const int M = in_sizes[0] / 128;   // 100000
    const int E = in_sizes[1];         // 1600000
    const int NBUK = (M + 511) / 512;  // 196
    const int T = (M + 15) / 16;
    const int GB = 512;

    char* ws = (char*)d_ws;
    size_t off = 0;
    auto alloc = [&](size_t bytes) -> void* {
        void* p = ws + off;
        off = (off + bytes + 511) & ~(size_t)511;
        return p;
    };
    int*   gbcnt  = (int*)alloc(256 * 4);
    int*   bbase  = (int*)alloc(256 * 4);
    int*   bcur   = (int*)alloc(256 * 4);
    int*   indptr = (int*)alloc((size_t)(M + 1) * 4);
    u32*   pairs  = (u32*)alloc((size_t)E * 4);
    int*   esrc   = (int*)alloc((size_t)E * 4);
    float* invdeg = (float*)alloc((size_t)M * 4);
    u16* bpack0 = (u16*)alloc(128 * 256 * 2);
    u16* bpack1 = (u16*)alloc(128 * 256 * 2);
    u16* bpack2 = (u16*)alloc(64 * 256 * 2);
    float* colstat0 = (float*)alloc(512 * 4);
    float* colstat1 = (float*)alloc(512 * 4);
    float* partials = (float*)alloc((size_t)GB * 256 * 4);
    u16*   hbuf   = (u16*)alloc((size_t)M * 128 * 2);   // bf16(x)
    u16*   aggbuf = (u16*)alloc((size_t)M * 128 * 2);
    u16*   preA   = (u16*)alloc((size_t)M * 128 * 2);   // layer0 pre-BN (bf16)
    u16*   preB   = (u16*)alloc((size_t)M * 128 * 2);   // layer1 pre-BN (bf16)
    float* preF   = (float*)alloc((size_t)M * 64 * 4);  // final logits (f32)
    u8*    x8     = (u8*)alloc((size_t)M * 128);        // fp8 gather tables
    u8*    preA8  = (u8*)alloc((size_t)M * 128);
    u8*    preB8  = (u8*)alloc((size_t)M * 128);

    // --- CSR build ---
    hipMemsetAsync(gbcnt, 0, 256 * 4, stream);
    bhist_kernel<<<(E + 8191) / 8192, 256, 0, stream>>>(dst, gbcnt, E);
    bscan_kernel<<<1, 256, 0, stream>>>(gbcnt, bbase, bcur, NBUK);
    bin_kernel<<<(E + BIN_TILE - 1) / BIN_TILE, 256, 0, stream>>>(src, dst, bcur, pairs, E, NBUK);
    sort2_kernel<<<NBUK, 256, 0, stream>>>(pairs, bbase, indptr, invdeg, esrc, M, E, NBUK);

    // --- bf16+fp8 convert + weight pack ---
    cvt_kernel<<<((M * 32) + 255) / 256, 256, 0, stream>>>(x, hbuf, (u32*)x8, M * 32);
    pack_kernel<<<(128 * 256 + 255) / 256, 256, 0, stream>>>(wself[0], wneigh[0], bpack0, 128);
    pack_kernel<<<(128 * 256 + 255) / 256, 256, 0, stream>>>(wself[1], wneigh[1], bpack1, 128);
    pack_kernel<<<(64 * 256 + 255) / 256, 256, 0, stream>>>(wself[2], wneigh[2], bpack2, 64);

    // --- layer 0 ---
    agg_kernel<false><<<(M + 3) / 4, 256, 0, stream>>>(x8, indptr, esrc, invdeg, nullptr, aggbuf, M);
    gemm2_kernel<4, true, false><<<GB, 256, 0, stream>>>(hbuf, aggbuf, bpack0, bias[0], nullptr,
                                                         preA, partials, M, T, GB * 2);
    hipMemsetAsync(colstat0, 0, 256 * 4, stream);
    bnred_kernel<<<32, 256, 0, stream>>>(partials, colstat0, GB);
    bnfin_kernel<<<1, 128, 0, stream>>>(colstat0, gamma[0], beta[0], 1.0f / (float)M);
    cvt8_kernel<<<((M * 16) + 255) / 256, 256, 0, stream>>>(preA, (uint2*)preA8, M * 16);

    // --- layer 1 ---
    agg_kernel<true><<<(M + 3) / 4, 256, 0, stream>>>(preA8, indptr, esrc, invdeg, colstat0, aggbuf, M);
    gemm2_kernel<4, true, true><<<GB, 256, 0, stream>>>(preA, aggbuf, bpack1, bias[1], colstat0,
                                                        preB, partials, M, T, GB * 2);
    hipMemsetAsync(colstat1, 0, 256 * 4, stream);
    bnred_kernel<<<32, 256, 0, stream>>>(partials, colstat1, GB);
    bnfin_kernel<<<1, 128, 0, stream>>>(colstat1, gamma[1], beta[1], 1.0f / (float)M);
    cvt8_kernel<<<((M * 16) + 255) / 256, 256, 0, stream>>>(preB, (uint2*)preB8, M * 16);

    // --- layer 2 ---
    agg_kernel<true><<<(M + 3) / 4, 256, 0, stream>>>(preB8, indptr, esrc, invdeg, colstat1, aggbuf, M);
    gemm2_kernel<2, false, true><<<GB, 256, 0, stream>>>(preB, aggbuf, bpack2, bias[2], colstat1,
                                                         preF, partials, M, T, GB * 2);
    lsm_kernel<<<(M + 3) / 4, 256, 0, stream>>>(preF, (float*)d_out, M);
}

// Round 13
// 510.397 us; speedup vs baseline: 1.6211x; 1.0441x over previous
//
#include <hip/hip_runtime.h>
#include <hip/hip_bf16.h>

typedef unsigned short u16;
typedef unsigned char  u8;
typedef unsigned int   u32;
typedef __attribute__((ext_vector_type(8))) short short8;
typedef __attribute__((ext_vector_type(4))) float floatx4;
typedef __attribute__((ext_vector_type(2))) float floatx2;

__device__ __forceinline__ float bits2f(u32 v){ float f; __builtin_memcpy(&f, &v, 4); return f; }
__device__ __forceinline__ u16 f2bf(float f){
    __hip_bfloat16 h = __float2bfloat16(f);
    u16 u; __builtin_memcpy(&u, &h, 2); return u;
}

// ---------------- f32 -> bf16 + fp8 conversion (x into hbuf, x8) ----------------

__global__ __launch_bounds__(256) void cvt_kernel(const float* __restrict__ in,
                                                  u16* __restrict__ out,
                                                  u32* __restrict__ out8, int total4){
    int i = blockIdx.x * 256 + threadIdx.x;   // 4 floats per thread
    if (i >= total4) return;
    float4 v = ((const float4*)in)[i];
    uint2 o;
    o.x = (u32)f2bf(v.x) | ((u32)f2bf(v.y) << 16);
    o.y = (u32)f2bf(v.z) | ((u32)f2bf(v.w) << 16);
    ((uint2*)out)[i] = o;
    u32 p8 = (u32)__builtin_amdgcn_cvt_pk_fp8_f32(v.x, v.y, 0, false);
    p8     = (u32)__builtin_amdgcn_cvt_pk_fp8_f32(v.z, v.w, (int)p8, true);
    out8[i] = p8;
}

// ------- bf16 pre -> fp8 activated table: fp8(relu(pre*sc + sh)) (dense affine, not per-edge) -------

__global__ __launch_bounds__(256) void cvt8a_kernel(const u16* __restrict__ in,
                                                    const float* __restrict__ cs,
                                                    uint2* __restrict__ out8, int total8){
    int i = blockIdx.x * 256 + threadIdx.x;   // 8 bf16 per thread
    if (i >= total8) return;
    const int c0 = (i & 15) * 8;              // 128 channels per row, 16 threads/row
    uint4 v = ((const uint4*)in)[i];
    u32 w[4] = {v.x, v.y, v.z, v.w};
    float f[8];
    #pragma unroll
    for (int j = 0; j < 4; ++j){
        f[2*j]   = bits2f(w[j] << 16);
        f[2*j+1] = bits2f(w[j] & 0xffff0000u);
    }
    #pragma unroll
    for (int j = 0; j < 8; ++j)
        f[j] = fmaxf(fmaf(f[j], cs[256 + c0 + j], cs[384 + c0 + j]), 0.f);
    u32 lo = (u32)__builtin_amdgcn_cvt_pk_fp8_f32(f[0], f[1], 0, false);
    lo     = (u32)__builtin_amdgcn_cvt_pk_fp8_f32(f[2], f[3], (int)lo, true);
    u32 hi = (u32)__builtin_amdgcn_cvt_pk_fp8_f32(f[4], f[5], 0, false);
    hi     = (u32)__builtin_amdgcn_cvt_pk_fp8_f32(f[6], f[7], (int)hi, true);
    uint2 o; o.x = lo; o.y = hi;
    out8[i] = o;
}

// ---------------- CSR build: bucket hist -> bucket scan -> multisplit bin -> bucket sort ----------------

__global__ __launch_bounds__(256) void bhist_kernel(const int* __restrict__ dst,
                                                    int* __restrict__ gbcnt, int E){
    __shared__ int bc[256];
    const int t = threadIdx.x;
    bc[t] = 0;
    __syncthreads();
    const int tile0 = blockIdx.x * 8192;
    const int cnt = min(8192, E - tile0);
    for (int j = t; j < cnt; j += 256) atomicAdd(&bc[dst[tile0 + j] >> 9], 1);
    __syncthreads();
    if (bc[t] > 0) atomicAdd(&gbcnt[t], bc[t]);
}

__global__ __launch_bounds__(256) void bscan_kernel(const int* __restrict__ gbcnt,
                                                    int* __restrict__ bbase,
                                                    int* __restrict__ bcur, int nbuk){
    __shared__ int ws[4];
    const int t = threadIdx.x, lane = t & 63, wv = t >> 6;
    int v = (t < nbuk) ? gbcnt[t] : 0;
    int s = v;
    for (int off = 1; off < 64; off <<= 1){
        int n = __shfl_up(s, off);
        if (lane >= off) s += n;
    }
    if (lane == 63) ws[wv] = s;
    __syncthreads();
    int woff = 0;
    for (int w = 0; w < wv; ++w) woff += ws[w];
    int excl = s + woff - v;
    if (t < nbuk){ bbase[t] = excl; bcur[t] = excl; }
}

#define BIN_TILE 8192
__global__ __launch_bounds__(256) void bin_kernel(const int* __restrict__ src,
                                                  const int* __restrict__ dst,
                                                  int* __restrict__ bcur,
                                                  u32* __restrict__ pairs, int E, int nbuk){
    __shared__ u32 hcnt[256], hexcl[256], hoff[256];
    __shared__ int gbase[256];
    __shared__ u32 stage[BIN_TILE];
    __shared__ unsigned char bkt[BIN_TILE];
    const int t = threadIdx.x;
    const int tile0 = blockIdx.x * BIN_TILE;
    const int cntE = min(BIN_TILE, E - tile0);

    hcnt[t] = 0;
    __syncthreads();
    for (int j = t; j < cntE; j += 256){
        int d = dst[tile0 + j];
        atomicAdd(&hcnt[d >> 9], 1u);
    }
    __syncthreads();
    if (t < 64){
        u32 a0 = hcnt[4*t], a1 = hcnt[4*t+1], a2 = hcnt[4*t+2], a3 = hcnt[4*t+3];
        u32 lsum = a0 + a1 + a2 + a3;
        u32 s = lsum;
        for (int off = 1; off < 64; off <<= 1){
            u32 n = __shfl_up(s, off);
            if (t >= off) s += n;
        }
        u32 base = s - lsum;
        hexcl[4*t]   = base;
        hexcl[4*t+1] = base + a0;
        hexcl[4*t+2] = base + a0 + a1;
        hexcl[4*t+3] = base + a0 + a1 + a2;
        hoff[4*t]   = base;
        hoff[4*t+1] = base + a0;
        hoff[4*t+2] = base + a0 + a1;
        hoff[4*t+3] = base + a0 + a1 + a2;
    }
    __syncthreads();
    if (t < nbuk && hcnt[t] > 0) gbase[t] = atomicAdd(&bcur[t], (int)hcnt[t]);
    for (int j = t; j < cntE; j += 256){
        int d = dst[tile0 + j];
        int s = src[tile0 + j];
        int b = d >> 9;
        u32 p = atomicAdd(&hoff[b], 1u);
        stage[p] = ((u32)s << 9) | (u32)(d & 511);
        bkt[p] = (unsigned char)b;
    }
    __syncthreads();
    for (int j = t; j < cntE; j += 256){
        int b = bkt[j];
        pairs[gbase[b] + (int)((u32)j - hexcl[b])] = stage[j];
    }
}

__global__ __launch_bounds__(256) void sort2_kernel(const u32* __restrict__ pairs,
                                                    const int* __restrict__ bbase,
                                                    int* __restrict__ indptr,
                                                    float* __restrict__ invdeg,
                                                    int* __restrict__ esrc,
                                                    int M, int E, int nbuk){
    __shared__ int ndeg[512];
    __shared__ int cur[512];
    __shared__ int wsI[4];
    const int b = blockIdx.x;
    const int node0 = b * 512;
    const int lo = bbase[b];
    const int hi = (b + 1 < nbuk) ? bbase[b + 1] : E;
    const int t = threadIdx.x, lane = t & 63, wv = t >> 6;

    ndeg[t] = 0; ndeg[t + 256] = 0;
    __syncthreads();
    for (int i = lo + t; i < hi; i += 256) atomicAdd(&ndeg[pairs[i] & 511], 1);
    __syncthreads();

    const int d0 = ndeg[2*t], d1 = ndeg[2*t + 1];
    const int p = d0 + d1;
    int s = p;
    for (int off = 1; off < 64; off <<= 1){
        int n = __shfl_up(s, off);
        if (lane >= off) s += n;
    }
    if (lane == 63) wsI[wv] = s;
    __syncthreads();
    int woff = 0;
    for (int w = 0; w < wv; ++w) woff += wsI[w];
    const int incl = s + woff;
    const int excl0 = incl - p;
    const int excl1 = excl0 + d0;

    const int n0 = node0 + 2*t, n1 = node0 + 2*t + 1;
    if (n0 < M){
        indptr[n0 + 1] = lo + excl0 + d0;
        invdeg[n0] = 1.0f / (float)max(d0, 1);
        cur[2*t] = lo + excl0;
    }
    if (n1 < M){
        indptr[n1 + 1] = lo + excl1 + d1;
        invdeg[n1] = 1.0f / (float)max(d1, 1);
        cur[2*t + 1] = lo + excl1;
    }
    if (b == 0 && t == 0) indptr[0] = 0;
    __syncthreads();
    for (int i = lo + t; i < hi; i += 256){
        u32 v = pairs[i];
        int pos = atomicAdd(&cur[v & 511], 1);
        esrc[pos] = (int)(v >> 9);
    }
}

// ------- weight packing -------

__global__ void pack_kernel(const float* __restrict__ wself, const float* __restrict__ wneigh,
                            u16* __restrict__ bp, int N){
    int i = blockIdx.x * 256 + threadIdx.x;
    if (i >= N * 256) return;
    int n = i >> 8, k = i & 255;
    float v = (k < 128) ? wself[k * N + n] : wneigh[(k - 128) * N + n];
    bp[i] = f2bf(v);
}

// ---------------- aggregation over fp8 table: 8 lanes/edge, 16 B/lane, 8 edges/instruction -------

__global__ __launch_bounds__(256) void agg_kernel(const u8* __restrict__ h8,
                                                  const int* __restrict__ indptr,
                                                  const int* __restrict__ esrc,
                                                  const float* __restrict__ invdeg,
                                                  u16* __restrict__ agg, int M){
    const int wave = threadIdx.x >> 6;
    const int lane = threadIdx.x & 63;
    const int g  = lane >> 3;    // edge subgroup 0..7
    const int l8 = lane & 7;     // 16-B chunk (16 fp8 channels)
    const int n = blockIdx.x * 4 + wave;
    if (n >= M) return;

    const int beg = indptr[n], end = indptr[n + 1];
    floatx2 acc[8];
    #pragma unroll
    for (int i = 0; i < 8; ++i){ acc[i].x = 0.f; acc[i].y = 0.f; }

    for (int e0 = beg; e0 < end; e0 += 32){
        uint4 v[4];
        #pragma unroll
        for (int u = 0; u < 4; ++u){
            int e = e0 + u * 8 + g;
            if (e < end){
                int idx = esrc[e];
                v[u] = *(const uint4*)(h8 + (size_t)idx * 128 + l8 * 16);
            }
        }
        #pragma unroll
        for (int u = 0; u < 4; ++u){
            int e = e0 + u * 8 + g;
            if (e < end){
                u32 w[4] = {v[u].x, v[u].y, v[u].z, v[u].w};
                #pragma unroll
                for (int j = 0; j < 4; ++j){
                    acc[2*j]   += __builtin_amdgcn_cvt_pk_f32_fp8(w[j], false);
                    acc[2*j+1] += __builtin_amdgcn_cvt_pk_f32_fp8(w[j], true);
                }
            }
        }
    }

    float s[16];
    #pragma unroll
    for (int j = 0; j < 8; ++j){ s[2*j] = acc[j].x; s[2*j+1] = acc[j].y; }
    #pragma unroll
    for (int k = 0; k < 16; ++k){
        s[k] += __shfl_xor(s[k], 8);
        s[k] += __shfl_xor(s[k], 16);
        s[k] += __shfl_xor(s[k], 32);
    }

    if (g == 0){
        float fs = invdeg[n];
        u32 o[8];
        #pragma unroll
        for (int k = 0; k < 8; ++k)
            o[k] = (u32)f2bf(s[2*k] * fs) | ((u32)f2bf(s[2*k+1] * fs) << 16);
        uint4 w0 = {o[0], o[1], o[2], o[3]};
        uint4 w1 = {o[4], o[5], o[6], o[7]};
        *(uint4*)(agg + (size_t)n * 128 + l8 * 16)     = w0;
        *(uint4*)(agg + (size_t)n * 128 + l8 * 16 + 8) = w1;
    }
}

// ------- GEMM: B pinned in registers, A streamed (ping-pong), fused bias + BN stats -------

template<int NTW, bool STATS, bool AFFA>
__global__ __launch_bounds__(256, 2) void gemm2_kernel(const u16* __restrict__ hA,
                                                       const u16* __restrict__ aggA,
                                                       const u16* __restrict__ Bp,
                                                       const float* __restrict__ bias,
                                                       const float* __restrict__ cs,
                                                       void* __restrict__ outPre,
                                                       float* __restrict__ partials,
                                                       int M, int T, int nstream){
    constexpr int N = NTW * 32;
    __shared__ float sbuf[4][N], s2buf[4][N];
    __shared__ float s_sc[128], s_sh[128];
    const int wave = threadIdx.x >> 6;
    const int lane = threadIdx.x & 63;
    const int m15 = lane & 15;
    const int quad = lane >> 4;
    const int colbase = (wave & 1) * (NTW * 16);

    if (STATS){
        for (int i = threadIdx.x; i < 4 * N; i += 256){
            ((float*)sbuf)[i] = 0.f;
            ((float*)s2buf)[i] = 0.f;
        }
    }
    if (AFFA && threadIdx.x < 128){
        s_sc[threadIdx.x] = cs[256 + threadIdx.x];
        s_sh[threadIdx.x] = cs[384 + threadIdx.x];
    }
    if (STATS || AFFA) __syncthreads();

    short8 breg[NTW][8];
    float bv[NTW];
    #pragma unroll
    for (int nt = 0; nt < NTW; ++nt){
        bv[nt] = bias[colbase + nt * 16 + m15];
        #pragma unroll
        for (int k0 = 0; k0 < 8; ++k0)
            breg[nt][k0] = *(const short8*)(Bp + (size_t)(colbase + nt * 16 + m15) * 256 + k0 * 32 + quad * 8);
    }

    float sS[NTW], sQ[NTW];
    #pragma unroll
    for (int nt = 0; nt < NTW; ++nt){ sS[nt] = 0.f; sQ[nt] = 0.f; }

    auto loadA = [&](short8* buf, int tile){
        int arow = tile * 16 + m15;
        if (arow >= M) arow = M - 1;
        const u16* p0 = hA   + (size_t)arow * 128 + quad * 8;
        const u16* p1 = aggA + (size_t)arow * 128 + quad * 8;
        #pragma unroll
        for (int k0 = 0; k0 < 4; ++k0) buf[k0]     = *(const short8*)(p0 + k0 * 32);
        #pragma unroll
        for (int k0 = 0; k0 < 4; ++k0) buf[4 + k0] = *(const short8*)(p1 + k0 * 32);
    };

    auto compute = [&](short8* buf, int tile){
        if (AFFA){
            #pragma unroll
            for (int k0 = 0; k0 < 4; ++k0){
                const int cb = k0 * 32 + quad * 8;
                short8 raw = buf[k0];
                #pragma unroll
                for (int j = 0; j < 8; ++j){
                    float f = bits2f(((u32)(u16)raw[j]) << 16);
                    f = fmaxf(fmaf(f, s_sc[cb + j], s_sh[cb + j]), 0.f);
                    raw[j] = (short)f2bf(f);
                }
                buf[k0] = raw;
            }
        }
        floatx4 acc[NTW];
        #pragma unroll
        for (int nt = 0; nt < NTW; ++nt) acc[nt] = 0.0f;
        #pragma unroll
        for (int k0 = 0; k0 < 8; ++k0)
            #pragma unroll
            for (int nt = 0; nt < NTW; ++nt)
                acc[nt] = __builtin_amdgcn_mfma_f32_16x16x32_bf16(buf[k0], breg[nt][k0], acc[nt], 0, 0, 0);
        const int row0 = tile * 16 + quad * 4;
        #pragma unroll
        for (int nt = 0; nt < NTW; ++nt){
            const int col = colbase + nt * 16 + m15;
            #pragma unroll
            for (int r = 0; r < 4; ++r){
                int row = row0 + r;
                if (row < M){
                    float v = acc[nt][r] + bv[nt];
                    if (STATS){
                        ((u16*)outPre)[(size_t)row * N + col] = f2bf(v);
                        sS[nt] += v;
                        sQ[nt] = fmaf(v, v, sQ[nt]);
                    } else {
                        ((float*)outPre)[(size_t)row * N + col] = v;
                    }
                }
            }
        }
    };

    short8 A0[8], A1[8];
    int t = blockIdx.x * 2 + (wave >> 1);
    const int stride = nstream;
    if (t < T){
        loadA(A0, t);
        while (true){
            int tn = t + stride;
            if (tn < T) loadA(A1, tn);
            compute(A0, t);
            t = tn;
            if (t >= T) break;
            tn = t + stride;
            if (tn < T) loadA(A0, tn);
            compute(A1, t);
            t = tn;
            if (t >= T) break;
        }
    }

    if (STATS){
        #pragma unroll
        for (int nt = 0; nt < NTW; ++nt){
            float s = sS[nt], q = sQ[nt];
            s += __shfl_xor(s, 16);  s += __shfl_xor(s, 32);
            q += __shfl_xor(q, 16);  q += __shfl_xor(q, 32);
            if (lane < 16){
                sbuf[wave][colbase + nt * 16 + m15] = s;
                s2buf[wave][colbase + nt * 16 + m15] = q;
            }
        }
        __syncthreads();
        const int c = threadIdx.x;
        if (c < N){
            float S  = sbuf[0][c] + sbuf[1][c] + sbuf[2][c] + sbuf[3][c];
            float S2 = s2buf[0][c] + s2buf[1][c] + s2buf[2][c] + s2buf[3][c];
            partials[(size_t)blockIdx.x * (2 * N) + c]     = S;
            partials[(size_t)blockIdx.x * (2 * N) + N + c] = S2;
        }
    }
}

// ---------------- BN: reduce block partials; finalize scale/shift ----------------

__global__ __launch_bounds__(256) void bnred_kernel(const float* __restrict__ partials,
                                                    float* __restrict__ cs, int nblk){
    const int t = threadIdx.x;
    float s = 0.f;
    for (int b = blockIdx.x; b < nblk; b += (int)gridDim.x)
        s += partials[(size_t)b * 256 + t];
    atomicAdd(&cs[t], s);
}

__global__ void bnfin_kernel(float* __restrict__ cs, const float* __restrict__ gamma,
                             const float* __restrict__ beta, float invM){
    int c = threadIdx.x;  // 128
    float mu  = cs[c] * invM;
    float var = fmaxf(cs[128 + c] * invM - mu * mu, 0.0f);
    float sc  = gamma[c] * rsqrtf(var + 1e-5f);
    cs[256 + c] = sc;
    cs[384 + c] = beta[c] - mu * sc;
}

// ---------------- log_softmax (one wave per 64-wide row) ----------------

__global__ __launch_bounds__(256) void lsm_kernel(const float* __restrict__ pre,
                                                  float* __restrict__ out, int M){
    const int wave = threadIdx.x >> 6;
    const int lane = threadIdx.x & 63;
    const int row = blockIdx.x * 4 + wave;
    if (row >= M) return;
    float v = pre[(size_t)row * 64 + lane];
    float m = v;
    #pragma unroll
    for (int o = 32; o; o >>= 1) m = fmaxf(m, __shfl_xor(m, o));
    float e = __expf(v - m);
    float s = e;
    #pragma unroll
    for (int o = 32; o; o >>= 1) s += __shfl_xor(s, o);
    out[(size_t)row * 64 + lane] = v - m - __logf(s);
}

// ---------------- host ----------------

extern "C" void kernel_launch(void* const* d_in, const int* in_sizes, int n_in,
                              void* d_out, int out_size, void* d_ws, size_t ws_size,
                              hipStream_t stream) {
    const float* x   = (const float*)d_in[0];
    const int*   src = (const int*)d_in[1];
    const int*   dst = (const int*)d_in[2];
    const float* wself[3]  = {(const float*)d_in[3], (const float*)d_in[6], (const float*)d_in[9]};
    const float* wneigh[3] = {(const float*)d_in[4], (const float*)d_in[7], (const float*)d_in[10]};
    const float* bias[3]   = {(const float*)d_in[5], (const float*)d_in[8], (const float*)d_in[11]};
    const float* gamma[2]  = {(const float*)d_in[12], (const float*)d_in[14]};
    const float* beta[2]   = {(const float*)d_in[13], (const float*)d_in[15]};

    const int M = in_sizes[0] / 128;   // 100000
    const int E = in_sizes[1];         // 1600000
    const int NBUK = (M + 511) / 512;  // 196
    const int T = (M + 15) / 16;
    const int GB = 512;

    char* ws = (char*)d_ws;
    size_t off = 0;
    auto alloc = [&](size_t bytes) -> void* {
        void* p = ws + off;
        off = (off + bytes + 511) & ~(size_t)511;
        return p;
    };
    int*   gbcnt  = (int*)alloc(256 * 4);
    int*   bbase  = (int*)alloc(256 * 4);
    int*   bcur   = (int*)alloc(256 * 4);
    int*   indptr = (int*)alloc((size_t)(M + 1) * 4);
    u32*   pairs  = (u32*)alloc((size_t)E * 4);
    int*   esrc   = (int*)alloc((size_t)E * 4);
    float* invdeg = (float*)alloc((size_t)M * 4);
    u16* bpack0 = (u16*)alloc(128 * 256 * 2);
    u16* bpack1 = (u16*)alloc(128 * 256 * 2);
    u16* bpack2 = (u16*)alloc(64 * 256 * 2);
    float* colstat0 = (float*)alloc(512 * 4);
    float* colstat1 = (float*)alloc(512 * 4);
    float* partials = (float*)alloc((size_t)GB * 256 * 4);
    u16*   hbuf   = (u16*)alloc((size_t)M * 128 * 2);   // bf16(x)
    u16*   aggbuf = (u16*)alloc((size_t)M * 128 * 2);
    u16*   preA   = (u16*)alloc((size_t)M * 128 * 2);   // layer0 pre-BN (bf16)
    u16*   preB   = (u16*)alloc((size_t)M * 128 * 2);   // layer1 pre-BN (bf16)
    float* preF   = (float*)alloc((size_t)M * 64 * 4);  // final logits (f32)
    u8*    x8     = (u8*)alloc((size_t)M * 128);        // fp8 gather tables (activated for L1/L2)
    u8*    preA8  = (u8*)alloc((size_t)M * 128);
    u8*    preB8  = (u8*)alloc((size_t)M * 128);

    // --- CSR build ---
    hipMemsetAsync(gbcnt, 0, 256 * 4, stream);
    bhist_kernel<<<(E + 8191) / 8192, 256, 0, stream>>>(dst, gbcnt, E);
    bscan_kernel<<<1, 256, 0, stream>>>(gbcnt, bbase, bcur, NBUK);
    bin_kernel<<<(E + BIN_TILE - 1) / BIN_TILE, 256, 0, stream>>>(src, dst, bcur, pairs, E, NBUK);
    sort2_kernel<<<NBUK, 256, 0, stream>>>(pairs, bbase, indptr, invdeg, esrc, M, E, NBUK);

    // --- bf16+fp8 convert + weight pack ---
    cvt_kernel<<<((M * 32) + 255) / 256, 256, 0, stream>>>(x, hbuf, (u32*)x8, M * 32);
    pack_kernel<<<(128 * 256 + 255) / 256, 256, 0, stream>>>(wself[0], wneigh[0], bpack0, 128);
    pack_kernel<<<(128 * 256 + 255) / 256, 256, 0, stream>>>(wself[1], wneigh[1], bpack1, 128);
    pack_kernel<<<(64 * 256 + 255) / 256, 256, 0, stream>>>(wself[2], wneigh[2], bpack2, 64);

    // --- layer 0 ---
    agg_kernel<<<(M + 3) / 4, 256, 0, stream>>>(x8, indptr, esrc, invdeg, aggbuf, M);
    gemm2_kernel<4, true, false><<<GB, 256, 0, stream>>>(hbuf, aggbuf, bpack0, bias[0], nullptr,
                                                         preA, partials, M, T, GB * 2);
    hipMemsetAsync(colstat0, 0, 256 * 4, stream);
    bnred_kernel<<<32, 256, 0, stream>>>(partials, colstat0, GB);
    bnfin_kernel<<<1, 128, 0, stream>>>(colstat0, gamma[0], beta[0], 1.0f / (float)M);
    cvt8a_kernel<<<((M * 16) + 255) / 256, 256, 0, stream>>>(preA, colstat0, (uint2*)preA8, M * 16);

    // --- layer 1 (fp8 table already activated; agg is affine-free) ---
    agg_kernel<<<(M + 3) / 4, 256, 0, stream>>>(preA8, indptr, esrc, invdeg, aggbuf, M);
    gemm2_kernel<4, true, true><<<GB, 256, 0, stream>>>(preA, aggbuf, bpack1, bias[1], colstat0,
                                                        preB, partials, M, T, GB * 2);
    hipMemsetAsync(colstat1, 0, 256 * 4, stream);
    bnred_kernel<<<32, 256, 0, stream>>>(partials, colstat1, GB);
    bnfin_kernel<<<1, 128, 0, stream>>>(colstat1, gamma[1], beta[1], 1.0f / (float)M);
    cvt8a_kernel<<<((M * 16) + 255) / 256, 256, 0, stream>>>(preB, colstat1, (uint2*)preB8, M * 16);

    // --- layer 2 ---
    agg_kernel<<<(M + 3) / 4, 256, 0, stream>>>(preB8, indptr, esrc, invdeg, aggbuf, M);
    gemm2_kernel<2, false, true><<<GB, 256, 0, stream>>>(preB, aggbuf, bpack2, bias[2], colstat1,
                                                         preF, partials, M, T, GB * 2);
    lsm_kernel<<<(M + 3) / 4, 256, 0, stream>>>(preF, (float*)d_out, M);
}